// Round 5
// baseline (135.349 us; speedup 1.0000x reference)
//
#include <hip/hip_runtime.h>

#define Bb 32
#define Nn 4096
#define Dd 256
#define Hh 256
#define NCH 32
#define CHUNK 128
#define NSTEPS 16   // K = 512 (Q:256 then K:256), steps of 32

typedef __attribute__((ext_vector_type(8))) short bf16x8;
typedef __attribute__((ext_vector_type(4))) float f32x4;

__device__ __forceinline__ unsigned short bf16_rtn(float x) {
    unsigned int u = __float_as_uint(x);
    u += 0x7FFF + ((u >> 16) & 1);
    return (unsigned short)(u >> 16);
}
__device__ __forceinline__ float bf16_to_f(unsigned short b) {
    return __uint_as_float(((unsigned int)b) << 16);
}
__device__ __forceinline__ float fast_tanhf(float x) {
    float e = __expf(2.0f * x);
    return 1.0f - 2.0f / (e + 1.0f);
}

// Truncation split of 8 f32 -> hi/lo bf16x8, packed with v_perm_b32.
__device__ __forceinline__ void split8_store(short* hp, short* lp, f32x4 v0, f32x4 v1) {
    float xs[8] = {v0.x, v0.y, v0.z, v0.w, v1.x, v1.y, v1.z, v1.w};
    unsigned int hu[4], lu[4];
#pragma unroll
    for (int p = 0; p < 4; ++p) {
        unsigned int u0 = __float_as_uint(xs[2 * p]);
        unsigned int u1 = __float_as_uint(xs[2 * p + 1]);
        float r0 = xs[2 * p]     - __uint_as_float(u0 & 0xFFFF0000u);
        float r1 = xs[2 * p + 1] - __uint_as_float(u1 & 0xFFFF0000u);
        hu[p] = __builtin_amdgcn_perm(u1, u0, 0x07060302u);
        lu[p] = __builtin_amdgcn_perm(__float_as_uint(r1), __float_as_uint(r0), 0x07060302u);
    }
    *(uint4*)hp = make_uint4(hu[0], hu[1], hu[2], hu[3]);
    *(uint4*)lp = make_uint4(lu[0], lu[1], lu[2], lu[3]);
}

// ---------------------------------------------------------------------------
// Prep: split Wcat = [Wq ; Wk] (H=256 rows, K=512 cols) into hi/lo bf16 blobs
// in fragment-linear order: blob[s][j][l][e] = Wcat[j*16+(l&15)][s*32+(l>>4)*8+e]
// ---------------------------------------------------------------------------
__global__ __launch_bounds__(256) void prep_w_kernel(
    const float* __restrict__ Wq, const float* __restrict__ Wk,
    short* __restrict__ Wh, short* __restrict__ Wl)
{
    const int g = blockIdx.x * 256 + threadIdx.x;      // [0, 16384)
    const int s = g >> 10;
    const int j = (g >> 6) & 15;
    const int l = g & 63;
    const int n = j * 16 + (l & 15);
    const int k = s * 32 + (l >> 4) * 8;
    const float* src = (k < 256) ? (Wq + n * 256 + k) : (Wk + n * 256 + (k - 256));
    const f32x4 v0 = *(const f32x4*)src;
    const f32x4 v1 = *(const f32x4*)(src + 4);
    float xs[8] = {v0.x, v0.y, v0.z, v0.w, v1.x, v1.y, v1.z, v1.w};
    bf16x8 h8, l8;
#pragma unroll
    for (int e = 0; e < 8; ++e) {
        unsigned short hb = bf16_rtn(xs[e]);
        float rem = xs[e] - bf16_to_f(hb);
        h8[e] = (short)hb;
        l8[e] = (short)bf16_rtn(rem);
    }
    *(bf16x8*)&Wh[(size_t)g * 8] = h8;
    *(bf16x8*)&Wl[(size_t)g * 8] = l8;
}

// ---------------------------------------------------------------------------
// Scores via split-bf16 MFMA. Block = 128 rows x 256 h, 4 waves; wave w owns
// cols [64w, 64w+64): m=8 x n=4 tiles of 16x16x32.
// Raw barriers (lgkmcnt(0) only) keep global loads in flight across steps:
// step s: cluster(buf[s%3]) -> split(set loaded s-1)->buf[(s+1)%3]
//         -> issue_b(s+1) -> issue_a(set, s+2) -> lgkm(0)+s_barrier.
// FIFO vmem order [B, A] means cluster waits vmcnt(4) (A prefetch survives).
// ---------------------------------------------------------------------------
__global__ __launch_bounds__(256, 2) void scores_mfma_kernel(
    const float* __restrict__ Q, const float* __restrict__ Kmat,
    const short* __restrict__ Wh, const short* __restrict__ Wl,
    const float* __restrict__ Wv, float* __restrict__ scores)
{
    __shared__ short Ah[3][4096];      // [buf][(m*64+lane)*8+e] hi  (24 KB)
    __shared__ short Al[3][4096];      // lo                         (24 KB)
    __shared__ float red[4][128];

    const int tid = threadIdx.x;
    const int lane = tid & 63;
    const int wave = tid >> 6;
    const size_t row0 = (size_t)blockIdx.x * 128;

    f32x4 acc[8][4];
#pragma unroll
    for (int m = 0; m < 8; ++m)
#pragma unroll
        for (int n = 0; n < 4; ++n) acc[m][n] = (f32x4){0.f, 0.f, 0.f, 0.f};

    float wv[4];
#pragma unroll
    for (int n = 0; n < 4; ++n) wv[n] = Wv[wave * 64 + n * 16 + (lane & 15)];

    // staging: thread t owns frag slots t and t+256. slot s: m=s>>6, l=s&63,
    // row = m*16+(l&15), k-chunk = ((l>>4)&3)*8. 128B-coalesced global reads.
    const int r_s0 = ((tid >> 6) << 4) + (tid & 15);
    const int r_s1 = r_s0 + 64;
    const int k_s0 = ((tid >> 4) & 3) * 8;

    // two in-flight A register sets: P = even-step data, Q = odd-step data
    f32x4 pA0, pA1, pA2, pA3;
    f32x4 qA0, qA1, qA2, qA3;
    bf16x8 bh[4], bl[4];

    auto issue_aP = [&](int s) {
        const float* Asrc = (s < 8) ? Q : Kmat;
        const int kb = (s & 7) * 32 + k_s0;
        const float* p0 = Asrc + (row0 + r_s0) * Dd + kb;
        const float* p1 = Asrc + (row0 + r_s1) * Dd + kb;
        pA0 = *(const f32x4*)p0; pA1 = *(const f32x4*)(p0 + 4);
        pA2 = *(const f32x4*)p1; pA3 = *(const f32x4*)(p1 + 4);
    };
    auto issue_aQ = [&](int s) {
        const float* Asrc = (s < 8) ? Q : Kmat;
        const int kb = (s & 7) * 32 + k_s0;
        const float* p0 = Asrc + (row0 + r_s0) * Dd + kb;
        const float* p1 = Asrc + (row0 + r_s1) * Dd + kb;
        qA0 = *(const f32x4*)p0; qA1 = *(const f32x4*)(p0 + 4);
        qA2 = *(const f32x4*)p1; qA3 = *(const f32x4*)(p1 + 4);
    };
    auto issue_b = [&](int s) {
#pragma unroll
        for (int n = 0; n < 4; ++n) {
            const size_t bo = ((size_t)(s * 16 + wave * 4 + n) * 64 + lane) * 8;
            bh[n] = *(const bf16x8*)(Wh + bo);
            bl[n] = *(const bf16x8*)(Wl + bo);
        }
    };
    auto splitP = [&](int buf) {
        split8_store(&Ah[buf][tid * 8], &Al[buf][tid * 8], pA0, pA1);
        split8_store(&Ah[buf][(tid + 256) * 8], &Al[buf][(tid + 256) * 8], pA2, pA3);
    };
    auto splitQ = [&](int buf) {
        split8_store(&Ah[buf][tid * 8], &Al[buf][tid * 8], qA0, qA1);
        split8_store(&Ah[buf][(tid + 256) * 8], &Al[buf][(tid + 256) * 8], qA2, qA3);
    };
    auto cluster = [&](int rb) {
        const short* ahb = &Ah[rb][0];
        const short* alb = &Al[rb][0];
        __builtin_amdgcn_s_setprio(1);
#pragma unroll
        for (int m = 0; m < 8; ++m) {
            const bf16x8 ahm = *(const bf16x8*)&ahb[(m * 64 + lane) * 8];
            const bf16x8 alm = *(const bf16x8*)&alb[(m * 64 + lane) * 8];
#pragma unroll
            for (int n = 0; n < 4; ++n) {
                acc[m][n] = __builtin_amdgcn_mfma_f32_16x16x32_bf16(ahm, bh[n], acc[m][n], 0, 0, 0);
                acc[m][n] = __builtin_amdgcn_mfma_f32_16x16x32_bf16(alm, bh[n], acc[m][n], 0, 0, 0);
                acc[m][n] = __builtin_amdgcn_mfma_f32_16x16x32_bf16(ahm, bl[n], acc[m][n], 0, 0, 0);
            }
        }
        __builtin_amdgcn_s_setprio(0);
    };
    auto barrier_nv = [&]() {              // LDS-ordering barrier; vmem stays in flight
        asm volatile("s_waitcnt lgkmcnt(0)" ::: "memory");
        __builtin_amdgcn_s_barrier();
        asm volatile("" ::: "memory");
    };

    // prologue: P<-step0, Q<-step1, B<-step0; split step0 into LDS[0]
    issue_aP(0);
    issue_aQ(1);
    issue_b(0);
    splitP(0);            // waits P only (counted vmcnt; Q,B stay in flight)
    barrier_nv();

    // hot loop: steps 0..13 (branch-free), then peel 14,15
    int rb = 0;
    for (int s2 = 0; s2 < 7; ++s2) {
        const int s = 2 * s2;
        const int rb1 = (rb == 2) ? 0 : rb + 1;
        const int rb2 = (rb1 == 2) ? 0 : rb1 + 1;
        // even step s
        cluster(rb);          // waits B(s) complete -> vmcnt(4); A prefetch survives
        splitQ(rb1);          // data step s+1 (loaded at s-1)
        issue_b(s + 1);
        issue_aP(s + 2);
        barrier_nv();
        // odd step s+1
        cluster(rb1);
        splitP(rb2);          // data step s+2 (loaded at s)
        issue_b(s + 2);
        issue_aQ(s + 3);
        barrier_nv();
        rb = rb2;
    }
    // step 14 (rb == 2)
    cluster(2);
    splitQ(0);                // step-15 data (loaded at step 13)
    issue_b(15);
    barrier_nv();
    // step 15
    cluster(0);

    // Epilogue: score_row += Wv[col] * tanh(acc). C/D: col=lane&15,
    // row = m*16 + (lane>>4)*4 + r. Fixed-order reduce -> deterministic.
    const int q = lane >> 4;
    float rp[8][4];
#pragma unroll
    for (int m = 0; m < 8; ++m)
#pragma unroll
        for (int r = 0; r < 4; ++r) {
            float v = 0.f;
#pragma unroll
            for (int n = 0; n < 4; ++n)
                v += wv[n] * fast_tanhf(acc[m][n][r]);
            rp[m][r] = v;
        }
#pragma unroll
    for (int mask = 1; mask <= 8; mask <<= 1)
#pragma unroll
        for (int m = 0; m < 8; ++m)
#pragma unroll
            for (int r = 0; r < 4; ++r)
                rp[m][r] += __shfl_xor(rp[m][r], mask, 64);

    if ((lane & 15) == 0) {
#pragma unroll
        for (int m = 0; m < 8; ++m)
#pragma unroll
            for (int r = 0; r < 4; ++r)
                red[wave][m * 16 + q * 4 + r] = rp[m][r];
    }
    __syncthreads();
    if (tid < 128)
        scores[row0 + tid] = (red[0][tid] + red[1][tid]) + (red[2][tid] + red[3][tid]);
}

// ---------------------------------------------------------------------------
// Per-b max + first-index argmax + sum(exp). Writes argmax output.
// ---------------------------------------------------------------------------
__global__ __launch_bounds__(256) void softmax_reduce_kernel(
    const float* __restrict__ scores, float* __restrict__ mbuf,
    float* __restrict__ zbuf, float* __restrict__ out)
{
    __shared__ float sv[256];
    __shared__ int si[256];
    const int b = blockIdx.x;
    const int tid = threadIdx.x;
    const float* sc = scores + (size_t)b * Nn;

    float best = -1e30f; int bi = 0;
    for (int j = 0; j < Nn / 256; ++j) {
        const int n = tid + j * 256;
        const float v = sc[n];
        if (v > best) { best = v; bi = n; }
    }
    sv[tid] = best; si[tid] = bi;
    __syncthreads();
    for (int off = 128; off > 0; off >>= 1) {
        if (tid < off) {
            const float v2 = sv[tid + off]; const int i2 = si[tid + off];
            if (v2 > sv[tid] || (v2 == sv[tid] && i2 < si[tid])) { sv[tid] = v2; si[tid] = i2; }
        }
        __syncthreads();
    }
    const float m = sv[0];
    const int amax = si[0];
    __syncthreads();

    float ssum = 0.f;
    for (int j = 0; j < Nn / 256; ++j) ssum += __expf(sc[tid + j * 256] - m);
    sv[tid] = ssum;
    __syncthreads();
    for (int off = 128; off > 0; off >>= 1) {
        if (tid < off) sv[tid] += sv[tid + off];
        __syncthreads();
    }
    if (tid == 0) {
        mbuf[b] = m;
        zbuf[b] = sv[0];
        out[(size_t)Bb * Dd + b] = (float)amax;
    }
}

// ---------------------------------------------------------------------------
// Partial out over n-chunks (no atomics; fixed-order accumulation)
// ---------------------------------------------------------------------------
__global__ __launch_bounds__(256) void partial_kernel(
    const float* __restrict__ V, const float* __restrict__ scores,
    const float* __restrict__ mbuf, float* __restrict__ part)
{
    __shared__ float e[CHUNK];
    const int c = blockIdx.x;
    const int b = blockIdx.y;
    const int tid = threadIdx.x;
    const float m = mbuf[b];
    if (tid < CHUNK)
        e[tid] = __expf(scores[(size_t)b * Nn + (size_t)c * CHUNK + tid] - m);
    __syncthreads();

    const float* vp = V + ((size_t)b * Nn + (size_t)c * CHUNK) * Dd + tid;
    float a0 = 0.f, a1 = 0.f, a2 = 0.f, a3 = 0.f;
    for (int n = 0; n < CHUNK; n += 4) {
        a0 = fmaf(e[n + 0], vp[(size_t)(n + 0) * Dd], a0);
        a1 = fmaf(e[n + 1], vp[(size_t)(n + 1) * Dd], a1);
        a2 = fmaf(e[n + 2], vp[(size_t)(n + 2) * Dd], a2);
        a3 = fmaf(e[n + 3], vp[(size_t)(n + 3) * Dd], a3);
    }
    part[((size_t)b * NCH + c) * Dd + tid] = ((a0 + a1) + (a2 + a3));
}

__global__ __launch_bounds__(256) void finalize_kernel(
    const float* __restrict__ part, const float* __restrict__ zbuf,
    float* __restrict__ out)
{
    const int b = blockIdx.x;
    const int tid = threadIdx.x;
    float s = 0.f;
#pragma unroll
    for (int c = 0; c < NCH; ++c) s += part[((size_t)b * NCH + c) * Dd + tid];
    out[(size_t)b * Dd + tid] = s / zbuf[b];
}

extern "C" void kernel_launch(void* const* d_in, const int* in_sizes, int n_in,
                              void* d_out, int out_size, void* d_ws, size_t ws_size,
                              hipStream_t stream) {
    const float* Q  = (const float*)d_in[0];
    const float* K  = (const float*)d_in[1];
    const float* V  = (const float*)d_in[2];
    const float* Wq = (const float*)d_in[3];
    const float* Wk = (const float*)d_in[4];
    const float* Wv = (const float*)d_in[5];
    float* out = (float*)d_out;

    // ws layout (bytes): Wh[256K] | Wl[256K] | scores[512K] | m[128] | z[128] | part[1M]
    char* wsb = (char*)d_ws;
    short* Wh     = (short*)(wsb);
    short* Wl     = (short*)(wsb + 262144);
    float* scores = (float*)(wsb + 524288);
    float* mbuf   = (float*)(wsb + 1048576);
    float* zbuf   = (float*)(wsb + 1048576 + 128);
    float* part   = (float*)(wsb + 1048576 + 256);

    prep_w_kernel<<<dim3(64), dim3(256), 0, stream>>>(Wq, Wk, Wh, Wl);
    scores_mfma_kernel<<<dim3((Bb * Nn) / 128), dim3(256), 0, stream>>>(Q, K, Wh, Wl, Wv, scores);
    softmax_reduce_kernel<<<dim3(Bb), dim3(256), 0, stream>>>(scores, mbuf, zbuf, out);
    partial_kernel<<<dim3(NCH, Bb), dim3(256), 0, stream>>>(V, scores, mbuf, part);
    finalize_kernel<<<dim3(Bb), dim3(256), 0, stream>>>(part, zbuf, out);
}

// Round 6
// 123.315 us; speedup vs baseline: 1.0976x; 1.0976x over previous
//
#include <hip/hip_runtime.h>

#define Bb 32
#define Nn 4096
#define Dd 256
#define Hh 256
#define NCH 32
#define CHUNK 128
#define NSTEPS 16   // K = 512 (Q:256 then K:256), steps of 32

typedef __attribute__((ext_vector_type(8))) _Float16 half8;
typedef __attribute__((ext_vector_type(4))) float f32x4;

__device__ __forceinline__ float fast_tanhf(float x) {
    float e = __expf(2.0f * x);
    return 1.0f - 2.0f / (e + 1.0f);
}

__device__ __forceinline__ half8 cvt8(f32x4 v0, f32x4 v1) {
    half8 h;
    h[0] = (_Float16)v0.x; h[1] = (_Float16)v0.y;
    h[2] = (_Float16)v0.z; h[3] = (_Float16)v0.w;
    h[4] = (_Float16)v1.x; h[5] = (_Float16)v1.y;
    h[6] = (_Float16)v1.z; h[7] = (_Float16)v1.w;
    return h;
}

// ---------------------------------------------------------------------------
// Prep: Wcat = [Wq ; Wk] (H=256 rows, K=512 cols) -> f16 blob, fragment-linear:
// Wf[s][j][l][e] = (f16) Wcat[j*16+(l&15)][s*32+(l>>4)*8+e]
// ---------------------------------------------------------------------------
__global__ __launch_bounds__(256) void prep_w_kernel(
    const float* __restrict__ Wq, const float* __restrict__ Wk,
    _Float16* __restrict__ Wf)
{
    const int g = blockIdx.x * 256 + threadIdx.x;      // [0, 16384)
    const int s = g >> 10;
    const int j = (g >> 6) & 15;
    const int l = g & 63;
    const int n = j * 16 + (l & 15);
    const int k = s * 32 + (l >> 4) * 8;
    const float* src = (k < 256) ? (Wq + n * 256 + k) : (Wk + n * 256 + (k - 256));
    const f32x4 v0 = *(const f32x4*)src;
    const f32x4 v1 = *(const f32x4*)(src + 4);
    *(half8*)&Wf[(size_t)g * 8] = cvt8(v0, v1);
}

// ---------------------------------------------------------------------------
// Scores via single f16 MFMA (RNE-rounded A and B; argmax protected by the
// f64 safety net in softmax_reduce). Block = 128 rows x 256 h, 4 waves;
// wave w owns cols [64w, 64w+64): m=8 x n=4 tiles of 16x16x32.
// A pipeline depth 2 (P/Q reg sets), LDS triple-buffered f16 frag-linear;
// B reg-double-buffered (BA/BB) from L2-resident prep blob.
// ---------------------------------------------------------------------------
__global__ __launch_bounds__(256, 2) void scores_mfma_kernel(
    const float* __restrict__ Q, const float* __restrict__ Kmat,
    const _Float16* __restrict__ Wf,
    const float* __restrict__ Wv, float* __restrict__ scores)
{
    __shared__ _Float16 Ahf[3][4096];   // [buf][(m*64+lane)*8+e]  (8 KB each)
    __shared__ float red[4][128];

    const int tid = threadIdx.x;
    const int lane = tid & 63;
    const int wave = tid >> 6;
    const size_t row0 = (size_t)blockIdx.x * 128;

    f32x4 acc[8][4];
#pragma unroll
    for (int m = 0; m < 8; ++m)
#pragma unroll
        for (int n = 0; n < 4; ++n) acc[m][n] = (f32x4){0.f, 0.f, 0.f, 0.f};

    float wv[4];
#pragma unroll
    for (int n = 0; n < 4; ++n) wv[n] = Wv[wave * 64 + n * 16 + (lane & 15)];

    // staging: thread t owns frag slots t and t+256. slot s: m=s>>6, l=s&63,
    // row = m*16+(l&15), k-chunk = ((l>>4)&3)*8. 128B-line-coalesced reads.
    const int r_s0 = ((tid >> 6) << 4) + (tid & 15);
    const int r_s1 = r_s0 + 64;
    const int k_s0 = ((tid >> 4) & 3) * 8;

    f32x4 pA0, pA1, pA2, pA3;          // P: even-step data
    f32x4 qA0, qA1, qA2, qA3;          // Q: odd-step data
    half8 BA[4], BB[4];

    auto issue_aP = [&](int s) {
        const float* Asrc = (s < 8) ? Q : Kmat;
        const int kb = (s & 7) * 32 + k_s0;
        const float* p0 = Asrc + (row0 + r_s0) * Dd + kb;
        const float* p1 = Asrc + (row0 + r_s1) * Dd + kb;
        pA0 = *(const f32x4*)p0; pA1 = *(const f32x4*)(p0 + 4);
        pA2 = *(const f32x4*)p1; pA3 = *(const f32x4*)(p1 + 4);
    };
    auto issue_aQ = [&](int s) {
        const float* Asrc = (s < 8) ? Q : Kmat;
        const int kb = (s & 7) * 32 + k_s0;
        const float* p0 = Asrc + (row0 + r_s0) * Dd + kb;
        const float* p1 = Asrc + (row0 + r_s1) * Dd + kb;
        qA0 = *(const f32x4*)p0; qA1 = *(const f32x4*)(p0 + 4);
        qA2 = *(const f32x4*)p1; qA3 = *(const f32x4*)(p1 + 4);
    };
    auto issue_bA = [&](int s) {
#pragma unroll
        for (int n = 0; n < 4; ++n)
            BA[n] = *(const half8*)(Wf + ((size_t)(s * 16 + wave * 4 + n) * 64 + lane) * 8);
    };
    auto issue_bB = [&](int s) {
#pragma unroll
        for (int n = 0; n < 4; ++n)
            BB[n] = *(const half8*)(Wf + ((size_t)(s * 16 + wave * 4 + n) * 64 + lane) * 8);
    };
    auto storeP = [&](int buf) {
        *(half8*)&Ahf[buf][tid * 8] = cvt8(pA0, pA1);
        *(half8*)&Ahf[buf][(tid + 256) * 8] = cvt8(pA2, pA3);
    };
    auto storeQ = [&](int buf) {
        *(half8*)&Ahf[buf][tid * 8] = cvt8(qA0, qA1);
        *(half8*)&Ahf[buf][(tid + 256) * 8] = cvt8(qA2, qA3);
    };
    auto clusterA = [&](int rb) {
        __builtin_amdgcn_s_setprio(1);
#pragma unroll
        for (int m = 0; m < 8; ++m) {
            const half8 ahm = *(const half8*)&Ahf[rb][(m * 64 + lane) * 8];
#pragma unroll
            for (int n = 0; n < 4; ++n)
                acc[m][n] = __builtin_amdgcn_mfma_f32_16x16x32_f16(ahm, BA[n], acc[m][n], 0, 0, 0);
        }
        __builtin_amdgcn_s_setprio(0);
    };
    auto clusterB = [&](int rb) {
        __builtin_amdgcn_s_setprio(1);
#pragma unroll
        for (int m = 0; m < 8; ++m) {
            const half8 ahm = *(const half8*)&Ahf[rb][(m * 64 + lane) * 8];
#pragma unroll
            for (int n = 0; n < 4; ++n)
                acc[m][n] = __builtin_amdgcn_mfma_f32_16x16x32_f16(ahm, BB[n], acc[m][n], 0, 0, 0);
        }
        __builtin_amdgcn_s_setprio(0);
    };

    // prologue: P<-A0, Q<-A1, BA<-B0; store A0 into LDS0
    issue_aP(0);
    issue_aQ(1);
    issue_bA(0);
    storeP(0);
    __syncthreads();

    // steady state (steps 0..13), rb(s) = s%3
    int rb = 0;
    for (int s2 = 0; s2 < 7; ++s2) {
        const int s = 2 * s2;
        const int rb1 = (rb == 2) ? 0 : rb + 1;
        const int rb2 = (rb1 == 2) ? 0 : rb1 + 1;
        // even step s: consume LDS[rb] with BA=B(s)
        issue_bB(s + 1);
        issue_aP(s + 2);
        clusterA(rb);
        storeQ(rb1);          // A(s+1), loaded at s-1
        __syncthreads();
        // odd step s+1: consume LDS[rb1] with BB=B(s+1)
        issue_bA(s + 2);
        issue_aQ(s + 3);
        clusterB(rb1);
        storeP(rb2);          // A(s+2), loaded at s
        __syncthreads();
        rb = rb2;
    }
    // step 14 (rb==2): BA=B14 (loaded at step 13)
    issue_bB(15);
    clusterA(2);
    storeQ(0);                // A15 (loaded at step 13)
    __syncthreads();
    // step 15
    clusterB(0);

    // Epilogue: score_row += Wv[col]*tanh(acc). C/D: col=lane&15,
    // row = m*16+(lane>>4)*4+r. Fixed-order reduce -> deterministic.
    const int q = lane >> 4;
    float rp[8][4];
#pragma unroll
    for (int m = 0; m < 8; ++m)
#pragma unroll
        for (int r = 0; r < 4; ++r) {
            float v = 0.f;
#pragma unroll
            for (int n = 0; n < 4; ++n)
                v += wv[n] * fast_tanhf(acc[m][n][r]);
            rp[m][r] = v;
        }
#pragma unroll
    for (int mask = 1; mask <= 8; mask <<= 1)
#pragma unroll
        for (int m = 0; m < 8; ++m)
#pragma unroll
            for (int r = 0; r < 4; ++r)
                rp[m][r] += __shfl_xor(rp[m][r], mask, 64);

    if ((lane & 15) == 0) {
#pragma unroll
        for (int m = 0; m < 8; ++m)
#pragma unroll
            for (int r = 0; r < 4; ++r)
                red[wave][m * 16 + q * 4 + r] = rp[m][r];
    }
    __syncthreads();
    if (tid < 128)
        scores[row0 + tid] = (red[0][tid] + red[1][tid]) + (red[2][tid] + red[3][tid]);
}

// ---------------------------------------------------------------------------
// Per-b max + argmax + sum(exp). Argmax protected by f64 safety net:
// candidates within tau of max are recomputed exactly (f64 accumulation);
// pick by (exact score, lowest index). Deterministic: the candidate SET is
// data-determined and the (value,index) argmax is order-independent.
// ---------------------------------------------------------------------------
#define MAXC 64
__global__ __launch_bounds__(256) void softmax_reduce_kernel(
    const float* __restrict__ scores,
    const float* __restrict__ Qg, const float* __restrict__ Kg,
    const float* __restrict__ Wq, const float* __restrict__ Wk,
    const float* __restrict__ Wv,
    float* __restrict__ mbuf, float* __restrict__ zbuf, float* __restrict__ out)
{
    __shared__ float sv[256];
    __shared__ int si[256];
    __shared__ double dred[256];
    __shared__ int cand[MAXC];
    __shared__ int cnt;
    const int b = blockIdx.x;
    const int tid = threadIdx.x;
    const float* sc = scores + (size_t)b * Nn;

    // pass 1: max + first-index argmax
    float best = -1e30f; int bi = 0;
    for (int j = 0; j < Nn / 256; ++j) {
        const int n = tid + j * 256;
        const float v = sc[n];
        if (v > best) { best = v; bi = n; }
    }
    sv[tid] = best; si[tid] = bi;
    __syncthreads();
    for (int off = 128; off > 0; off >>= 1) {
        if (tid < off) {
            const float v2 = sv[tid + off]; const int i2 = si[tid + off];
            if (v2 > sv[tid] || (v2 == sv[tid] && i2 < si[tid])) { sv[tid] = v2; si[tid] = i2; }
        }
        __syncthreads();
    }
    const float m = sv[0];
    int amax = si[0];
    __syncthreads();

    // pass 2: sum(exp)
    float ssum = 0.f;
    for (int j = 0; j < Nn / 256; ++j) ssum += __expf(sc[tid + j * 256] - m);
    sv[tid] = ssum;
    __syncthreads();
    for (int off = 128; off > 0; off >>= 1) {
        if (tid < off) sv[tid] += sv[tid + off];
        __syncthreads();
    }
    const float Z = sv[0];
    __syncthreads();

    // safety net: exact argmax among near-max candidates
    if (tid == 0) cnt = 0;
    __syncthreads();
    const float tau = 0.008f;   // >> 2x worst-case f16-GEMM score error (~2.4e-4 rms)
    for (int j = 0; j < Nn / 256; ++j) {
        const int n = tid + j * 256;
        if (sc[n] >= m - tau) {
            const int p = atomicAdd(&cnt, 1);
            if (p < MAXC) cand[p] = n;
        }
    }
    __syncthreads();
    const int ncand = (cnt < MAXC) ? cnt : MAXC;
    if (ncand > 1) {
        double bestv = -1e300; int besti = 0x7fffffff;
        for (int c = 0; c < ncand; ++c) {
            const int n = cand[c];
            const float* qr = Qg + ((size_t)b * Nn + n) * Dd;
            const float* kr = Kg + ((size_t)b * Nn + n) * Dd;
            const float* wqr = Wq + tid * Dd;
            const float* wkr = Wk + tid * Dd;
            double accd = 0.0;
            for (int k2 = 0; k2 < Dd; ++k2)
                accd += (double)qr[k2] * (double)wqr[k2] + (double)kr[k2] * (double)wkr[k2];
            dred[tid] = (double)Wv[tid] * tanh(accd);
            __syncthreads();
            for (int off = 128; off > 0; off >>= 1) {
                if (tid < off) dred[tid] += dred[tid + off];
                __syncthreads();
            }
            const double s_c = dred[0];
            __syncthreads();
            if (s_c > bestv || (s_c == bestv && n < besti)) { bestv = s_c; besti = n; }
        }
        amax = besti;
    }

    if (tid == 0) {
        mbuf[b] = m;
        zbuf[b] = Z;
        out[(size_t)Bb * Dd + b] = (float)amax;
    }
}

// ---------------------------------------------------------------------------
// Partial out over n-chunks (no atomics; fixed-order accumulation)
// ---------------------------------------------------------------------------
__global__ __launch_bounds__(256) void partial_kernel(
    const float* __restrict__ V, const float* __restrict__ scores,
    const float* __restrict__ mbuf, float* __restrict__ part)
{
    __shared__ float e[CHUNK];
    const int c = blockIdx.x;
    const int b = blockIdx.y;
    const int tid = threadIdx.x;
    const float m = mbuf[b];
    if (tid < CHUNK)
        e[tid] = __expf(scores[(size_t)b * Nn + (size_t)c * CHUNK + tid] - m);
    __syncthreads();

    const float* vp = V + ((size_t)b * Nn + (size_t)c * CHUNK) * Dd + tid;
    float a0 = 0.f, a1 = 0.f, a2 = 0.f, a3 = 0.f;
    for (int n = 0; n < CHUNK; n += 4) {
        a0 = fmaf(e[n + 0], vp[(size_t)(n + 0) * Dd], a0);
        a1 = fmaf(e[n + 1], vp[(size_t)(n + 1) * Dd], a1);
        a2 = fmaf(e[n + 2], vp[(size_t)(n + 2) * Dd], a2);
        a3 = fmaf(e[n + 3], vp[(size_t)(n + 3) * Dd], a3);
    }
    part[((size_t)b * NCH + c) * Dd + tid] = ((a0 + a1) + (a2 + a3));
}

__global__ __launch_bounds__(256) void finalize_kernel(
    const float* __restrict__ part, const float* __restrict__ zbuf,
    float* __restrict__ out)
{
    const int b = blockIdx.x;
    const int tid = threadIdx.x;
    float s = 0.f;
#pragma unroll
    for (int c = 0; c < NCH; ++c) s += part[((size_t)b * NCH + c) * Dd + tid];
    out[(size_t)b * Dd + tid] = s / zbuf[b];
}

extern "C" void kernel_launch(void* const* d_in, const int* in_sizes, int n_in,
                              void* d_out, int out_size, void* d_ws, size_t ws_size,
                              hipStream_t stream) {
    const float* Q  = (const float*)d_in[0];
    const float* K  = (const float*)d_in[1];
    const float* V  = (const float*)d_in[2];
    const float* Wq = (const float*)d_in[3];
    const float* Wk = (const float*)d_in[4];
    const float* Wv = (const float*)d_in[5];
    float* out = (float*)d_out;

    // ws layout (bytes): Wf[256K] | scores[512K] | m[128] | z[128] | part[1M]
    char* wsb = (char*)d_ws;
    _Float16* Wf  = (_Float16*)(wsb);
    float* scores = (float*)(wsb + 262144);
    float* mbuf   = (float*)(wsb + 786432);
    float* zbuf   = (float*)(wsb + 786432 + 128);
    float* part   = (float*)(wsb + 786432 + 256);

    prep_w_kernel<<<dim3(64), dim3(256), 0, stream>>>(Wq, Wk, Wf);
    scores_mfma_kernel<<<dim3((Bb * Nn) / 128), dim3(256), 0, stream>>>(Q, K, Wf, Wv, scores);
    softmax_reduce_kernel<<<dim3(Bb), dim3(256), 0, stream>>>(scores, Q, K, Wq, Wk, Wv, mbuf, zbuf, out);
    partial_kernel<<<dim3(NCH, Bb), dim3(256), 0, stream>>>(V, scores, mbuf, part);
    finalize_kernel<<<dim3(Bb), dim3(256), 0, stream>>>(part, zbuf, out);
}

// Round 7
// 122.972 us; speedup vs baseline: 1.1007x; 1.0028x over previous
//
#include <hip/hip_runtime.h>

#define Bb 32
#define Nn 4096
#define Dd 256
#define Hh 256
#define NCH 32
#define CHUNK 128
#define NSTEPS 16   // K = 512 (Q:256 then K:256), steps of 32

typedef __attribute__((ext_vector_type(8))) _Float16 half8;
typedef __attribute__((ext_vector_type(4))) float f32x4;

__device__ __forceinline__ float fast_tanhf(float x) {
    float e = __expf(2.0f * x);
    return 1.0f - 2.0f / (e + 1.0f);
}

__device__ __forceinline__ half8 cvt8(f32x4 v0, f32x4 v1) {
    half8 h;
    h[0] = (_Float16)v0.x; h[1] = (_Float16)v0.y;
    h[2] = (_Float16)v0.z; h[3] = (_Float16)v0.w;
    h[4] = (_Float16)v1.x; h[5] = (_Float16)v1.y;
    h[6] = (_Float16)v1.z; h[7] = (_Float16)v1.w;
    return h;
}

// ---------------------------------------------------------------------------
// Prep: Wcat = [Wq ; Wk] (H=256 rows, K=512 cols) -> f16 blob, fragment-linear:
// Wf[s][j][l][e] = (f16) Wcat[j*16+(l&15)][s*32+(l>>4)*8+e]
// ---------------------------------------------------------------------------
__global__ __launch_bounds__(256) void prep_w_kernel(
    const float* __restrict__ Wq, const float* __restrict__ Wk,
    _Float16* __restrict__ Wf)
{
    const int g = blockIdx.x * 256 + threadIdx.x;      // [0, 16384)
    const int s = g >> 10;
    const int j = (g >> 6) & 15;
    const int l = g & 63;
    const int n = j * 16 + (l & 15);
    const int k = s * 32 + (l >> 4) * 8;
    const float* src = (k < 256) ? (Wq + n * 256 + k) : (Wk + n * 256 + (k - 256));
    const f32x4 v0 = *(const f32x4*)src;
    const f32x4 v1 = *(const f32x4*)(src + 4);
    *(half8*)&Wf[(size_t)g * 8] = cvt8(v0, v1);
}

// ---------------------------------------------------------------------------
// Scores via single f16 MFMA (argmax protected by the f64 safety net in
// softmax_reduce). Block = 128 rows x 256 h, 4 waves; wave w owns cols
// [64w, 64w+64): m=8 x n=4 tiles of 16x16x32.
// A pipeline depth 2 (P/Q reg sets), LDS triple-buffered f16 frag-linear;
// B reg-double-buffered (BA/BB) from L2-resident prep blob.
// IN-LOOP BARRIERS ARE NON-DRAINING: s_waitcnt lgkmcnt(0) + s_barrier only,
// so the A(s+2)/B(s+1) prefetches stay in flight across the barrier and are
// consumed via compiler-emitted COUNTED vmcnt (never vmcnt(0) in the loop).
// ---------------------------------------------------------------------------
__global__ __launch_bounds__(256, 2) void scores_mfma_kernel(
    const float* __restrict__ Q, const float* __restrict__ Kmat,
    const _Float16* __restrict__ Wf,
    const float* __restrict__ Wv, float* __restrict__ scores)
{
    __shared__ _Float16 Ahf[3][4096];   // [buf][(m*64+lane)*8+e]  (8 KB each)
    __shared__ float red[4][128];

    const int tid = threadIdx.x;
    const int lane = tid & 63;
    const int wave = tid >> 6;
    const size_t row0 = (size_t)blockIdx.x * 128;

    f32x4 acc[8][4];
#pragma unroll
    for (int m = 0; m < 8; ++m)
#pragma unroll
        for (int n = 0; n < 4; ++n) acc[m][n] = (f32x4){0.f, 0.f, 0.f, 0.f};

    float wv[4];
#pragma unroll
    for (int n = 0; n < 4; ++n) wv[n] = Wv[wave * 64 + n * 16 + (lane & 15)];

    // staging: thread t owns frag slots t and t+256. slot s: m=s>>6, l=s&63,
    // row = m*16+(l&15), k-chunk = ((l>>4)&3)*8. 128B-line-coalesced reads.
    const int r_s0 = ((tid >> 6) << 4) + (tid & 15);
    const int r_s1 = r_s0 + 64;
    const int k_s0 = ((tid >> 4) & 3) * 8;

    f32x4 pA0, pA1, pA2, pA3;          // P: even-step data
    f32x4 qA0, qA1, qA2, qA3;          // Q: odd-step data
    half8 BA[4], BB[4];

    auto issue_aP = [&](int s) {
        const float* Asrc = (s < 8) ? Q : Kmat;
        const int kb = (s & 7) * 32 + k_s0;
        const float* p0 = Asrc + (row0 + r_s0) * Dd + kb;
        const float* p1 = Asrc + (row0 + r_s1) * Dd + kb;
        pA0 = *(const f32x4*)p0; pA1 = *(const f32x4*)(p0 + 4);
        pA2 = *(const f32x4*)p1; pA3 = *(const f32x4*)(p1 + 4);
    };
    auto issue_aQ = [&](int s) {
        const float* Asrc = (s < 8) ? Q : Kmat;
        const int kb = (s & 7) * 32 + k_s0;
        const float* p0 = Asrc + (row0 + r_s0) * Dd + kb;
        const float* p1 = Asrc + (row0 + r_s1) * Dd + kb;
        qA0 = *(const f32x4*)p0; qA1 = *(const f32x4*)(p0 + 4);
        qA2 = *(const f32x4*)p1; qA3 = *(const f32x4*)(p1 + 4);
    };
    auto issue_bA = [&](int s) {
#pragma unroll
        for (int n = 0; n < 4; ++n)
            BA[n] = *(const half8*)(Wf + ((size_t)(s * 16 + wave * 4 + n) * 64 + lane) * 8);
    };
    auto issue_bB = [&](int s) {
#pragma unroll
        for (int n = 0; n < 4; ++n)
            BB[n] = *(const half8*)(Wf + ((size_t)(s * 16 + wave * 4 + n) * 64 + lane) * 8);
    };
    auto storeP = [&](int buf) {
        *(half8*)&Ahf[buf][tid * 8] = cvt8(pA0, pA1);
        *(half8*)&Ahf[buf][(tid + 256) * 8] = cvt8(pA2, pA3);
    };
    auto storeQ = [&](int buf) {
        *(half8*)&Ahf[buf][tid * 8] = cvt8(qA0, qA1);
        *(half8*)&Ahf[buf][(tid + 256) * 8] = cvt8(qA2, qA3);
    };
    auto clusterA = [&](int rb) {
        __builtin_amdgcn_s_setprio(1);
#pragma unroll
        for (int m = 0; m < 8; ++m) {
            const half8 ahm = *(const half8*)&Ahf[rb][(m * 64 + lane) * 8];
#pragma unroll
            for (int n = 0; n < 4; ++n)
                acc[m][n] = __builtin_amdgcn_mfma_f32_16x16x32_f16(ahm, BA[n], acc[m][n], 0, 0, 0);
        }
        __builtin_amdgcn_s_setprio(0);
    };
    auto clusterB = [&](int rb) {
        __builtin_amdgcn_s_setprio(1);
#pragma unroll
        for (int m = 0; m < 8; ++m) {
            const half8 ahm = *(const half8*)&Ahf[rb][(m * 64 + lane) * 8];
#pragma unroll
            for (int n = 0; n < 4; ++n)
                acc[m][n] = __builtin_amdgcn_mfma_f32_16x16x32_f16(ahm, BB[n], acc[m][n], 0, 0, 0);
        }
        __builtin_amdgcn_s_setprio(0);
    };
    auto barrier_nv = [&]() {       // LDS-ordering barrier; vmem stays in flight
        asm volatile("s_waitcnt lgkmcnt(0)" ::: "memory");
        __builtin_amdgcn_s_barrier();
        asm volatile("" ::: "memory");
    };

    // prologue: P<-A0, Q<-A1, BA<-B0; store A0 into LDS0
    issue_aP(0);
    issue_aQ(1);
    issue_bA(0);
    storeP(0);           // counted vmcnt wait for P only; Q,BA stay in flight
    barrier_nv();

    // steady state (steps 0..13), rb(s) = s%3
    int rb = 0;
    for (int s2 = 0; s2 < 7; ++s2) {
        const int s = 2 * s2;
        const int rb1 = (rb == 2) ? 0 : rb + 1;
        const int rb2 = (rb1 == 2) ? 0 : rb1 + 1;
        // even step s: consume LDS[rb] with BA=B(s)
        issue_bB(s + 1);
        issue_aP(s + 2);
        clusterA(rb);
        storeQ(rb1);          // A(s+1), loaded at s-1
        barrier_nv();
        // odd step s+1: consume LDS[rb1] with BB=B(s+1)
        issue_bA(s + 2);
        issue_aQ(s + 3);
        clusterB(rb1);
        storeP(rb2);          // A(s+2), loaded at s
        barrier_nv();
        rb = rb2;
    }
    // step 14 (rb==2): BA=B14 (loaded at step 13)
    issue_bB(15);
    clusterA(2);
    storeQ(0);                // A15 (loaded at step 13)
    barrier_nv();
    // step 15
    clusterB(0);

    // Epilogue: score_row += Wv[col]*tanh(acc). C/D: col=lane&15,
    // row = m*16+(lane>>4)*4+r. Fixed-order reduce -> deterministic.
    const int q = lane >> 4;
    float rp[8][4];
#pragma unroll
    for (int m = 0; m < 8; ++m)
#pragma unroll
        for (int r = 0; r < 4; ++r) {
            float v = 0.f;
#pragma unroll
            for (int n = 0; n < 4; ++n)
                v += wv[n] * fast_tanhf(acc[m][n][r]);
            rp[m][r] = v;
        }
#pragma unroll
    for (int mask = 1; mask <= 8; mask <<= 1)
#pragma unroll
        for (int m = 0; m < 8; ++m)
#pragma unroll
            for (int r = 0; r < 4; ++r)
                rp[m][r] += __shfl_xor(rp[m][r], mask, 64);

    if ((lane & 15) == 0) {
#pragma unroll
        for (int m = 0; m < 8; ++m)
#pragma unroll
            for (int r = 0; r < 4; ++r)
                red[wave][m * 16 + q * 4 + r] = rp[m][r];
    }
    __syncthreads();
    if (tid < 128)
        scores[row0 + tid] = (red[0][tid] + red[1][tid]) + (red[2][tid] + red[3][tid]);
}

// ---------------------------------------------------------------------------
// Per-b max + argmax + sum(exp). Argmax protected by f64 safety net:
// candidates within tau of max are recomputed exactly (f64 accumulation);
// pick by (exact score, lowest index). Deterministic: the candidate SET is
// data-determined and the (value,index) argmax is order-independent.
// ---------------------------------------------------------------------------
#define MAXC 64
__global__ __launch_bounds__(256) void softmax_reduce_kernel(
    const float* __restrict__ scores,
    const float* __restrict__ Qg, const float* __restrict__ Kg,
    const float* __restrict__ Wq, const float* __restrict__ Wk,
    const float* __restrict__ Wv,
    float* __restrict__ mbuf, float* __restrict__ zbuf, float* __restrict__ out)
{
    __shared__ float sv[256];
    __shared__ int si[256];
    __shared__ double dred[256];
    __shared__ int cand[MAXC];
    __shared__ int cnt;
    const int b = blockIdx.x;
    const int tid = threadIdx.x;
    const float* sc = scores + (size_t)b * Nn;

    // pass 1: max + first-index argmax
    float best = -1e30f; int bi = 0;
    for (int j = 0; j < Nn / 256; ++j) {
        const int n = tid + j * 256;
        const float v = sc[n];
        if (v > best) { best = v; bi = n; }
    }
    sv[tid] = best; si[tid] = bi;
    __syncthreads();
    for (int off = 128; off > 0; off >>= 1) {
        if (tid < off) {
            const float v2 = sv[tid + off]; const int i2 = si[tid + off];
            if (v2 > sv[tid] || (v2 == sv[tid] && i2 < si[tid])) { sv[tid] = v2; si[tid] = i2; }
        }
        __syncthreads();
    }
    const float m = sv[0];
    int amax = si[0];
    __syncthreads();

    // pass 2: sum(exp)
    float ssum = 0.f;
    for (int j = 0; j < Nn / 256; ++j) ssum += __expf(sc[tid + j * 256] - m);
    sv[tid] = ssum;
    __syncthreads();
    for (int off = 128; off > 0; off >>= 1) {
        if (tid < off) sv[tid] += sv[tid + off];
        __syncthreads();
    }
    const float Z = sv[0];
    __syncthreads();

    // safety net: exact argmax among near-max candidates
    if (tid == 0) cnt = 0;
    __syncthreads();
    const float tau = 0.008f;   // >> 2x worst-case f16-GEMM score error (~2.4e-4 rms)
    for (int j = 0; j < Nn / 256; ++j) {
        const int n = tid + j * 256;
        if (sc[n] >= m - tau) {
            const int p = atomicAdd(&cnt, 1);
            if (p < MAXC) cand[p] = n;
        }
    }
    __syncthreads();
    const int ncand = (cnt < MAXC) ? cnt : MAXC;
    if (ncand > 1) {
        double bestv = -1e300; int besti = 0x7fffffff;
        for (int c = 0; c < ncand; ++c) {
            const int n = cand[c];
            const float* qr = Qg + ((size_t)b * Nn + n) * Dd;
            const float* kr = Kg + ((size_t)b * Nn + n) * Dd;
            const float* wqr = Wq + tid * Dd;
            const float* wkr = Wk + tid * Dd;
            double accd = 0.0;
            for (int k2 = 0; k2 < Dd; ++k2)
                accd += (double)qr[k2] * (double)wqr[k2] + (double)kr[k2] * (double)wkr[k2];
            dred[tid] = (double)Wv[tid] * tanh(accd);
            __syncthreads();
            for (int off = 128; off > 0; off >>= 1) {
                if (tid < off) dred[tid] += dred[tid + off];
                __syncthreads();
            }
            const double s_c = dred[0];
            __syncthreads();
            if (s_c > bestv || (s_c == bestv && n < besti)) { bestv = s_c; besti = n; }
        }
        amax = besti;
    }

    if (tid == 0) {
        mbuf[b] = m;
        zbuf[b] = Z;
        out[(size_t)Bb * Dd + b] = (float)amax;
    }
}

// ---------------------------------------------------------------------------
// Partial out over n-chunks (no atomics; fixed-order accumulation)
// ---------------------------------------------------------------------------
__global__ __launch_bounds__(256) void partial_kernel(
    const float* __restrict__ V, const float* __restrict__ scores,
    const float* __restrict__ mbuf, float* __restrict__ part)
{
    __shared__ float e[CHUNK];
    const int c = blockIdx.x;
    const int b = blockIdx.y;
    const int tid = threadIdx.x;
    const float m = mbuf[b];
    if (tid < CHUNK)
        e[tid] = __expf(scores[(size_t)b * Nn + (size_t)c * CHUNK + tid] - m);
    __syncthreads();

    const float* vp = V + ((size_t)b * Nn + (size_t)c * CHUNK) * Dd + tid;
    float a0 = 0.f, a1 = 0.f, a2 = 0.f, a3 = 0.f;
    for (int n = 0; n < CHUNK; n += 4) {
        a0 = fmaf(e[n + 0], vp[(size_t)(n + 0) * Dd], a0);
        a1 = fmaf(e[n + 1], vp[(size_t)(n + 1) * Dd], a1);
        a2 = fmaf(e[n + 2], vp[(size_t)(n + 2) * Dd], a2);
        a3 = fmaf(e[n + 3], vp[(size_t)(n + 3) * Dd], a3);
    }
    part[((size_t)b * NCH + c) * Dd + tid] = ((a0 + a1) + (a2 + a3));
}

__global__ __launch_bounds__(256) void finalize_kernel(
    const float* __restrict__ part, const float* __restrict__ zbuf,
    float* __restrict__ out)
{
    const int b = blockIdx.x;
    const int tid = threadIdx.x;
    float s = 0.f;
#pragma unroll
    for (int c = 0; c < NCH; ++c) s += part[((size_t)b * NCH + c) * Dd + tid];
    out[(size_t)b * Dd + tid] = s / zbuf[b];
}

extern "C" void kernel_launch(void* const* d_in, const int* in_sizes, int n_in,
                              void* d_out, int out_size, void* d_ws, size_t ws_size,
                              hipStream_t stream) {
    const float* Q  = (const float*)d_in[0];
    const float* K  = (const float*)d_in[1];
    const float* V  = (const float*)d_in[2];
    const float* Wq = (const float*)d_in[3];
    const float* Wk = (const float*)d_in[4];
    const float* Wv = (const float*)d_in[5];
    float* out = (float*)d_out;

    // ws layout (bytes): Wf[256K] | scores[512K] | m[128] | z[128] | part[1M]
    char* wsb = (char*)d_ws;
    _Float16* Wf  = (_Float16*)(wsb);
    float* scores = (float*)(wsb + 262144);
    float* mbuf   = (float*)(wsb + 786432);
    float* zbuf   = (float*)(wsb + 786432 + 128);
    float* part   = (float*)(wsb + 786432 + 256);

    prep_w_kernel<<<dim3(64), dim3(256), 0, stream>>>(Wq, Wk, Wf);
    scores_mfma_kernel<<<dim3((Bb * Nn) / 128), dim3(256), 0, stream>>>(Q, K, Wf, Wv, scores);
    softmax_reduce_kernel<<<dim3(Bb), dim3(256), 0, stream>>>(scores, Q, K, Wq, Wk, Wv, mbuf, zbuf, out);
    partial_kernel<<<dim3(NCH, Bb), dim3(256), 0, stream>>>(V, scores, mbuf, part);
    finalize_kernel<<<dim3(Bb), dim3(256), 0, stream>>>(part, zbuf, out);
}